// Round 2
// baseline (208.626 us; speedup 1.0000x reference)
//
#include <hip/hip_runtime.h>
#include <hip/hip_bf16.h>

typedef __bf16 bf16x8 __attribute__((ext_vector_type(8)));
typedef float  f32x4  __attribute__((ext_vector_type(4)));

// ---------------------------------------------------------------------------
// async global->LDS, 16B per lane. Dest is wave-uniform base + lane*16.
__device__ __forceinline__ void gload16(const __bf16* g, __bf16* l) {
  __builtin_amdgcn_global_load_lds(
      (const __attribute__((address_space(1))) void*)g,
      (__attribute__((address_space(3))) void*)l, 16, 0, 0);
}

// Stage a ROWSx64 bf16 tile into LDS. LDS written linearly (wave-uniform dest);
// global SOURCE is permuted so LDS content is XOR-swizzled: logical 16B-slot s
// of row r lives at phys slot s ^ (r&7). Reads apply the same XOR (rule 21).
// Each wave issues ROWS/64 global_load_lds instructions.
template <int ROWS>
__device__ __forceinline__ void stage(const __bf16* __restrict__ g, int ld,
                                      __bf16* l, int wid, int lane) {
#pragma unroll
  for (int p = 0; p < ROWS / 64; ++p) {
    int cbase = p * 512 + wid * 64;         // 16B chunk index of lane 0
    int c     = cbase + lane;
    int row   = c >> 3;                     // 8 chunks (128B) per row
    int slog  = (c & 7) ^ (row & 7);        // inverse-swizzled source slot
    gload16(g + (long)row * ld + slog * 8, l + cbase * 8);
  }
}

// swizzled LDS byte offset for logical (row, 16B-slot s)
__device__ __forceinline__ int lds_off(int r, int s) {
  return r * 128 + ((s * 16) ^ ((r & 7) << 4));
}

// ---------------------------------------------------------------------------
// C[M][N] = A[M][K] * Bt[N][K]^T  (row-major, K contiguous).
// 256x128 tile, BK=64, 512 threads = 8 waves (2 M x 4 N), wave out = 128x32.
// Triple-buffered LDS, distance-2 prefetch, counted vmcnt (T3/T4), setprio
// (T5), bijective XCD swizzle (T1; grid size must be a multiple of 8).
// OUTBF16: store __bf16 else float. BIASMODE: 0 none, 1 bias[col], 2 bias[row].
template <int OUTBF16, int BIASMODE, int DOSCALE>
__global__ __launch_bounds__(512, 1) void gemm_bt2(
    const __bf16* __restrict__ A, const __bf16* __restrict__ Bt,
    const float* __restrict__ bias, void* __restrict__ Cv,
    int lda, int ldb, int ldc, int K,
    long sA, long sB, long sC, float scale) {
  __shared__ __align__(16) __bf16 ldsA[3][256 * 64];  // 96 KiB
  __shared__ __align__(16) __bf16 ldsB[3][128 * 64];  // 48 KiB

  const int tid = threadIdx.x, wid = tid >> 6, lane = tid & 63;
  const int wr = wid >> 2, wc = wid & 3;

  // T1: XCD-aware bijective swizzle of the flat block id (nwg % 8 == 0)
  const int gx = gridDim.x, gy = gridDim.y;
  const int nwg = gx * gy * (int)gridDim.z;
  int flat = ((int)blockIdx.z * gy + (int)blockIdx.y) * gx + (int)blockIdx.x;
  flat = (flat & 7) * (nwg >> 3) + (flat >> 3);
  const int bx = flat % gx;
  const int by = (flat / gx) % gy;
  const int bz = flat / (gx * gy);

  const long brow = (long)by * 256;
  const long bcol = (long)bx * 128;
  const __bf16* ga = A + bz * sA + brow * lda;
  const __bf16* gb = Bt + bz * sB + bcol * ldb;
  const int nk = K >> 6;

  f32x4 acc[8][2];
#pragma unroll
  for (int m = 0; m < 8; ++m)
#pragma unroll
    for (int n = 0; n < 2; ++n) acc[m][n] = (f32x4){0.f, 0.f, 0.f, 0.f};

  // prologue: stage tiles 0,1
  stage<256>(ga, lda, ldsA[0], wid, lane);
  stage<128>(gb, ldb, ldsB[0], wid, lane);
  if (nk > 1) {
    stage<256>(ga + 64, lda, ldsA[1], wid, lane);
    stage<128>(gb + 64, ldb, ldsB[1], wid, lane);
  }

  for (int t = 0; t < nk; ++t) {
    // protect buf[(t+2)%3] (== buf[(t-1)%3], read last iter) before staging
    if (t > 0) asm volatile("s_barrier" ::: "memory");
    if (t + 2 < nk) {
      stage<256>(ga + (t + 2) * 64, lda, ldsA[(t + 2) % 3], wid, lane);
      stage<128>(gb + (t + 2) * 64, ldb, ldsB[(t + 2) % 3], wid, lane);
    }
    // counted wait: own tile-t loads landed (6 instr/tile/wave), then barrier
    // makes it a cross-wave guarantee. Never drains the t+1/t+2 prefetch.
    const int left = (nk - 1 - t) < 2 ? (nk - 1 - t) : 2;
    if (left == 2)
      asm volatile("s_waitcnt vmcnt(12)\n\ts_barrier" ::: "memory");
    else if (left == 1)
      asm volatile("s_waitcnt vmcnt(6)\n\ts_barrier" ::: "memory");
    else
      asm volatile("s_waitcnt vmcnt(0)\n\ts_barrier" ::: "memory");

    const char* Ab = (const char*)ldsA[t % 3];
    const char* Bb = (const char*)ldsB[t % 3];
#pragma unroll
    for (int ks = 0; ks < 2; ++ks) {
      const int s = ks * 4 + (lane >> 4);
      bf16x8 af[8], bfr[2];
#pragma unroll
      for (int m = 0; m < 8; ++m)
        af[m] = *(const bf16x8*)(Ab + lds_off(wr * 128 + m * 16 + (lane & 15), s));
#pragma unroll
      for (int n = 0; n < 2; ++n)
        bfr[n] = *(const bf16x8*)(Bb + lds_off(wc * 32 + n * 16 + (lane & 15), s));
      __builtin_amdgcn_s_setprio(1);
#pragma unroll
      for (int m = 0; m < 8; ++m)
#pragma unroll
        for (int n = 0; n < 2; ++n)
          acc[m][n] = __builtin_amdgcn_mfma_f32_16x16x32_bf16(
              af[m], bfr[n], acc[m][n], 0, 0, 0);
      __builtin_amdgcn_s_setprio(0);
    }
  }

  // epilogue: C/D layout col = lane&15, row = (lane>>4)*4 + reg
  const long cb = (long)bz * sC;
#pragma unroll
  for (int m = 0; m < 8; ++m) {
    const int row = (int)brow + wr * 128 + m * 16 + ((lane >> 4) << 2);
#pragma unroll
    for (int n = 0; n < 2; ++n) {
      const int col = (int)bcol + wc * 32 + n * 16 + (lane & 15);
#pragma unroll
      for (int r = 0; r < 4; ++r) {
        float v = acc[m][n][r];
        if (DOSCALE) v *= scale;
        if (BIASMODE == 1) v += bias[col];
        if (BIASMODE == 2) v += bias[row + r];
        if (OUTBF16)
          ((__bf16*)Cv)[cb + (long)(row + r) * ldc + col] = (__bf16)v;
        else
          ((float*)Cv)[cb + (long)(row + r) * ldc + col] = v;
      }
    }
  }
}

// ---------------------------------------------------------------------------
// x fp32 -> bf16, 8 elements/thread, exact coverage
__global__ __launch_bounds__(256) void convert_x(const float* __restrict__ x,
                                                 __bf16* __restrict__ o) {
  const long i = ((long)blockIdx.x * 256 + threadIdx.x) * 8;
  float4 a = *(const float4*)(x + i);
  float4 b = *(const float4*)(x + i + 4);
  bf16x8 v;
  v[0] = (__bf16)a.x; v[1] = (__bf16)a.y; v[2] = (__bf16)a.z; v[3] = (__bf16)a.w;
  v[4] = (__bf16)b.x; v[5] = (__bf16)b.y; v[6] = (__bf16)b.z; v[7] = (__bf16)b.w;
  *(bf16x8*)(o + i) = v;
}

// W[1024][1024] fp32 -> Wt[1024][1024] bf16 transposed; 64x64 tiles.
__global__ __launch_bounds__(256) void transpose_w(
    const float* __restrict__ W0, const float* __restrict__ W1,
    const float* __restrict__ W2, __bf16* __restrict__ T0,
    __bf16* __restrict__ T1, __bf16* __restrict__ T2) {
  const float* W = blockIdx.z == 0 ? W0 : (blockIdx.z == 1 ? W1 : W2);
  __bf16* T      = blockIdx.z == 0 ? T0 : (blockIdx.z == 1 ? T1 : T2);
  __shared__ float t[64][65];
  const int e0 = blockIdx.x * 64, d0 = blockIdx.y * 64;
  const int tr = threadIdx.x >> 2, tc = (threadIdx.x & 3) * 16;
  const float* src = W + (long)(d0 + tr) * 1024 + e0 + tc;
#pragma unroll
  for (int i = 0; i < 4; ++i) {
    float4 v = *(const float4*)(src + i * 4);
    t[tr][tc + i * 4 + 0] = v.x;
    t[tr][tc + i * 4 + 1] = v.y;
    t[tr][tc + i * 4 + 2] = v.z;
    t[tr][tc + i * 4 + 3] = v.w;
  }
  __syncthreads();
  __bf16* dst = T + (long)(e0 + tr) * 1024 + d0 + tc;
  bf16x8 v0, v1;
#pragma unroll
  for (int i = 0; i < 8; ++i) v0[i] = (__bf16)t[tc + i][tr];
#pragma unroll
  for (int i = 0; i < 8; ++i) v1[i] = (__bf16)t[tc + 8 + i][tr];
  *(bf16x8*)dst = v0;
  *(bf16x8*)(dst + 8) = v1;
}

// in-place row softmax over 2048 bf16, one block per row, fp32 reduction
__global__ __launch_bounds__(256) void softmax_rows(__bf16* __restrict__ P) {
  __bf16* p = P + (long)blockIdx.x * 2048;
  const int t = threadIdx.x, wid = t >> 6, lane = t & 63;
  bf16x8 v = *(bf16x8*)(p + t * 8);
  float f[8];
  float mx = -1e30f;
#pragma unroll
  for (int i = 0; i < 8; ++i) { f[i] = (float)v[i]; mx = fmaxf(mx, f[i]); }
#pragma unroll
  for (int o = 32; o > 0; o >>= 1) mx = fmaxf(mx, __shfl_xor(mx, o));
  __shared__ float redm[4], reds[4];
  if (lane == 0) redm[wid] = mx;
  __syncthreads();
  mx = fmaxf(fmaxf(redm[0], redm[1]), fmaxf(redm[2], redm[3]));
  float s = 0.f;
#pragma unroll
  for (int i = 0; i < 8; ++i) { f[i] = __expf(f[i] - mx); s += f[i]; }
#pragma unroll
  for (int o = 32; o > 0; o >>= 1) s += __shfl_xor(s, o);
  if (lane == 0) reds[wid] = s;
  __syncthreads();
  s = reds[0] + reds[1] + reds[2] + reds[3];
  const float inv = 1.0f / s;
#pragma unroll
  for (int i = 0; i < 8; ++i) v[i] = (__bf16)(f[i] * inv);
  *(bf16x8*)(p + t * 8) = v;
}

// ---------------------------------------------------------------------------
extern "C" void kernel_launch(void* const* d_in, const int* in_sizes, int n_in,
                              void* d_out, int out_size, void* d_ws,
                              size_t ws_size, hipStream_t stream) {
  const float* x  = (const float*)d_in[0];
  const float* Wq = (const float*)d_in[1];
  const float* bq = (const float*)d_in[2];
  const float* Wk = (const float*)d_in[3];
  const float* bk = (const float*)d_in[4];
  const float* Wv = (const float*)d_in[5];
  const float* bv = (const float*)d_in[6];
  float* out = (float*)d_out;

  char* ws = (char*)d_ws;
  __bf16* xb  = (__bf16*)(ws);                    // 16 MB: x bf16 [8192][1024]
  __bf16* wqt = (__bf16*)(ws + (16l << 20));      //  2 MB: Wq^T
  __bf16* wkt = (__bf16*)(ws + (18l << 20));      //  2 MB: Wk^T
  __bf16* wvt = (__bf16*)(ws + (20l << 20));      //  2 MB: Wv^T
  __bf16* q   = (__bf16*)(ws + (22l << 20));      // 16 MB: Q [8192][1024]
  __bf16* kk  = (__bf16*)(ws + (38l << 20));      // 16 MB: K [8192][1024]
  __bf16* vt  = (__bf16*)(ws + (54l << 20));      // 16 MB: V^T [1024][8192]
  __bf16* S   = (__bf16*)(ws + (70l << 20));      // 32 MB: S/P [4][2048][2048]

  convert_x<<<4096, 256, 0, stream>>>(x, xb);
  transpose_w<<<dim3(16, 16, 3), 256, 0, stream>>>(Wq, Wk, Wv, wqt, wkt, wvt);

  // Q = xb Wq + bq  (M=8192, N=1024, K=1024), bf16 out
  gemm_bt2<1, 1, 0><<<dim3(8, 32, 1), 512, 0, stream>>>(
      xb, wqt, bq, q, 1024, 1024, 1024, 1024, 0, 0, 0, 1.f);
  gemm_bt2<1, 1, 0><<<dim3(8, 32, 1), 512, 0, stream>>>(
      xb, wkt, bk, kk, 1024, 1024, 1024, 1024, 0, 0, 0, 1.f);
  // V^T directly: Vt[e][token] (M=1024 features, N=8192 tokens), bias per ROW
  gemm_bt2<1, 2, 0><<<dim3(64, 4, 1), 512, 0, stream>>>(
      wvt, xb, bv, vt, 1024, 1024, 8192, 1024, 0, 0, 0, 1.f);

  // S = Q K^T * (1/32)  per batch (M=N=2048, K=1024), bf16 out
  gemm_bt2<1, 0, 1><<<dim3(16, 8, 4), 512, 0, stream>>>(
      q, kk, nullptr, S, 1024, 1024, 2048, 1024,
      2048l * 1024, 2048l * 1024, 2048l * 2048, 0.03125f);

  softmax_rows<<<8192, 256, 0, stream>>>(S);

  // O = P V  per batch (M=2048, N=1024, K=2048), fp32 out to d_out.
  gemm_bt2<0, 0, 0><<<dim3(8, 8, 4), 512, 0, stream>>>(
      S, vt, nullptr, out, 2048, 8192, 1024, 2048,
      2048l * 2048, 2048, 2048l * 1024, 1.f);
}

// Round 3
// 176.192 us; speedup vs baseline: 1.1841x; 1.1841x over previous
//
#include <hip/hip_runtime.h>
#include <hip/hip_bf16.h>

typedef __bf16 bf16x8 __attribute__((ext_vector_type(8)));
typedef float  f32x4  __attribute__((ext_vector_type(4)));

// ---------------------------------------------------------------------------
// async global->LDS, 16B per lane. Dest is wave-uniform base + lane*16.
__device__ __forceinline__ void gload16(const __bf16* g, __bf16* l) {
  __builtin_amdgcn_global_load_lds(
      (const __attribute__((address_space(1))) void*)g,
      (__attribute__((address_space(3))) void*)l, 16, 0, 0);
}

// Stage one 128x64 bf16 unit (16 KiB) into LDS. LDS written linearly
// (wave-uniform dest); global SOURCE pre-permuted so LDS content is
// XOR-swizzled: logical 16B-slot s of row r lives at phys slot s ^ (r&7).
// 2 global_load_lds per wave.
__device__ __forceinline__ void stage_unit(const __bf16* __restrict__ g, int ld,
                                           __bf16* l, int wid, int lane) {
#pragma unroll
  for (int p = 0; p < 2; ++p) {
    int cbase = p * 512 + wid * 64;   // 16B chunk index of lane 0
    int c     = cbase + lane;
    int row   = c >> 3;               // 8 chunks (128B) per row
    int slog  = (c & 7) ^ (row & 7);  // inverse-swizzled source slot
    gload16(g + (long)row * ld + slog * 8, l + cbase * 8);
  }
}

// swizzled LDS byte offset for logical (row, 16B-slot s)
__device__ __forceinline__ int lds_off(int r, int s) {
  return r * 128 + ((s * 16) ^ ((r & 7) << 4));
}

// One K-tile = two fine phases (ks=0: stage A-halves of t+2; ks=1: stage B of
// t+2 + counted vmcnt). WAIT: 6 steady, 0 at t=nk-2, -1 at t=nk-1.
template <bool STAGE, int WAIT>
__device__ __forceinline__ void do_ktile(
    const __bf16* __restrict__ gaN, const __bf16* __restrict__ gbN,
    int lda, int ldb, const __bf16* lA, const __bf16* lB,
    __bf16* nA, __bf16* nB, int wid, int wr, int wc, int lane,
    f32x4 (&acc)[4][4]) {
  const int rl = lane & 15;
  const char* Ab = (const char*)lA;
  const char* Bb = (const char*)lB;
  bf16x8 af[4], bf[4];

  // ---------------- phase ks = 0 (slots 0..3)
#pragma unroll
  for (int m = 0; m < 4; ++m)
    af[m] = *(const bf16x8*)(Ab + lds_off(wr * 64 + m * 16 + rl, lane >> 4));
#pragma unroll
  for (int n = 0; n < 4; ++n)
    bf[n] = *(const bf16x8*)(Bb + lds_off(wc * 64 + n * 16 + rl, lane >> 4));
  if constexpr (STAGE) {
    stage_unit(gaN, lda, nA, wid, lane);                         // A rows 0-127
    stage_unit(gaN + 128l * lda, lda, nA + 128 * 64, wid, lane); // A rows 128+
  }
  __builtin_amdgcn_sched_barrier(0);
  __builtin_amdgcn_s_barrier();
  asm volatile("s_waitcnt lgkmcnt(0)" ::: "memory");
  __builtin_amdgcn_sched_barrier(0);
  __builtin_amdgcn_s_setprio(1);
#pragma unroll
  for (int m = 0; m < 4; ++m)
#pragma unroll
    for (int n = 0; n < 4; ++n)
      acc[m][n] = __builtin_amdgcn_mfma_f32_16x16x32_bf16(af[m], bf[n],
                                                          acc[m][n], 0, 0, 0);
  __builtin_amdgcn_s_setprio(0);
  __builtin_amdgcn_sched_barrier(0);
  __builtin_amdgcn_s_barrier();

  // ---------------- phase ks = 1 (slots 4..7)
#pragma unroll
  for (int m = 0; m < 4; ++m)
    af[m] = *(const bf16x8*)(Ab + lds_off(wr * 64 + m * 16 + rl, 4 + (lane >> 4)));
#pragma unroll
  for (int n = 0; n < 4; ++n)
    bf[n] = *(const bf16x8*)(Bb + lds_off(wc * 64 + n * 16 + rl, 4 + (lane >> 4)));
  if constexpr (STAGE) stage_unit(gbN, ldb, nB, wid, lane);
  if constexpr (WAIT == 6) asm volatile("s_waitcnt vmcnt(6)" ::: "memory");
  else if constexpr (WAIT == 0) asm volatile("s_waitcnt vmcnt(0)" ::: "memory");
  __builtin_amdgcn_sched_barrier(0);
  __builtin_amdgcn_s_barrier();
  asm volatile("s_waitcnt lgkmcnt(0)" ::: "memory");
  __builtin_amdgcn_sched_barrier(0);
  __builtin_amdgcn_s_setprio(1);
#pragma unroll
  for (int m = 0; m < 4; ++m)
#pragma unroll
    for (int n = 0; n < 4; ++n)
      acc[m][n] = __builtin_amdgcn_mfma_f32_16x16x32_bf16(af[m], bf[n],
                                                          acc[m][n], 0, 0, 0);
  __builtin_amdgcn_s_setprio(0);
  __builtin_amdgcn_sched_barrier(0);
  __builtin_amdgcn_s_barrier();
}

// ---------------------------------------------------------------------------
// C[M][N] = A[M][K] * Bt[N][K]^T  (row-major, K contiguous).
// 256x128 tile, BK=64, 512 thr = 8 waves (4M x 2N), wave out 64x64.
// 3-buffer LDS (144 KiB), distance-2 prefetch, per-K-tile counted vmcnt(6),
// fine 2-phase interleave, setprio, bijective XCD swizzle (nwg % 8 == 0).
// OUTBF16: bf16 vs float out. BIASMODE: 0 none, 1 col-pair(bias/bias2 at
// col 1024 split), 2 bias[row]. DOSCALE: scale before bias/store.
template <int OUTBF16, int BIASMODE, int DOSCALE>
__global__ __launch_bounds__(512, 2) void gemm3(
    const __bf16* __restrict__ A, const __bf16* __restrict__ Bt,
    const float* __restrict__ bias, const float* __restrict__ bias2,
    void* __restrict__ Cv, int lda, int ldb, int ldc, int K,
    long sA, long sB, long sC, float scale) {
  __shared__ __align__(16) __bf16 ldsA[3][256 * 64];  // 96 KiB
  __shared__ __align__(16) __bf16 ldsB[3][128 * 64];  // 48 KiB

  const int tid = threadIdx.x, wid = tid >> 6, lane = tid & 63;
  const int wr = wid >> 1, wc = wid & 1;

  // T1: bijective XCD swizzle of flat block id
  const int gx = gridDim.x, gy = gridDim.y;
  const int nwg = gx * gy * (int)gridDim.z;
  int flat = ((int)blockIdx.z * gy + (int)blockIdx.y) * gx + (int)blockIdx.x;
  flat = (flat & 7) * (nwg >> 3) + (flat >> 3);
  const int bx = flat % gx;
  const int by = (flat / gx) % gy;
  const int bz = flat / (gx * gy);

  const long brow = (long)by * 256;
  const long bcol = (long)bx * 128;
  const __bf16* ga = A + bz * sA + brow * lda;
  const __bf16* gb = Bt + bz * sB + bcol * ldb;
  const int nk = K >> 6;

  f32x4 acc[4][4];
#pragma unroll
  for (int m = 0; m < 4; ++m)
#pragma unroll
    for (int n = 0; n < 4; ++n) acc[m][n] = (f32x4){0.f, 0.f, 0.f, 0.f};

  // prologue: stage K-tiles 0,1 (A0,A1,B each) -> 12 loads/wave
  stage_unit(ga, lda, ldsA[0], wid, lane);
  stage_unit(ga + 128l * lda, lda, ldsA[0] + 128 * 64, wid, lane);
  stage_unit(gb, ldb, ldsB[0], wid, lane);
  stage_unit(ga + 64, lda, ldsA[1], wid, lane);
  stage_unit(ga + 64 + 128l * lda, lda, ldsA[1] + 128 * 64, wid, lane);
  stage_unit(gb + 64, ldb, ldsB[1], wid, lane);
  asm volatile("s_waitcnt vmcnt(6)" ::: "memory");  // K-tile 0 landed
  __builtin_amdgcn_s_barrier();

  __bf16 *a0 = ldsA[0], *a1 = ldsA[1], *a2 = ldsA[2];
  __bf16 *b0 = ldsB[0], *b1 = ldsB[1], *b2 = ldsB[2];
  for (int t = 0; t < nk - 2; ++t) {
    do_ktile<true, 6>(ga + (t + 2) * 64, gb + (t + 2) * 64, lda, ldb,
                      a0, b0, a2, b2, wid, wr, wc, lane, acc);
    __bf16* ta = a0; a0 = a1; a1 = a2; a2 = ta;
    __bf16* tb = b0; b0 = b1; b1 = b2; b2 = tb;
  }
  do_ktile<false, 0>(ga, gb, lda, ldb, a0, b0, a2, b2, wid, wr, wc, lane, acc);
  do_ktile<false, -1>(ga, gb, lda, ldb, a1, b1, a2, b2, wid, wr, wc, lane, acc);

  // epilogue: C/D layout col = lane&15, row = (lane>>4)*4 + reg
  const long cb = (long)bz * sC;
#pragma unroll
  for (int m = 0; m < 4; ++m) {
    const int row = (int)brow + wr * 64 + m * 16 + ((lane >> 4) << 2);
#pragma unroll
    for (int n = 0; n < 4; ++n) {
      const int col = (int)bcol + wc * 64 + n * 16 + (lane & 15);
#pragma unroll
      for (int r = 0; r < 4; ++r) {
        float v = acc[m][n][r];
        if (DOSCALE) v *= scale;
        if (BIASMODE == 1) v += (col < 1024) ? bias[col] : bias2[col - 1024];
        if (BIASMODE == 2) v += bias[row + r];
        if (OUTBF16)
          ((__bf16*)Cv)[cb + (long)(row + r) * ldc + col] = (__bf16)v;
        else
          ((float*)Cv)[cb + (long)(row + r) * ldc + col] = v;
      }
    }
  }
}

// ---------------------------------------------------------------------------
// x fp32 -> bf16, 8 elements/thread, exact coverage
__global__ __launch_bounds__(256) void convert_x(const float* __restrict__ x,
                                                 __bf16* __restrict__ o) {
  const long i = ((long)blockIdx.x * 256 + threadIdx.x) * 8;
  float4 a = *(const float4*)(x + i);
  float4 b = *(const float4*)(x + i + 4);
  bf16x8 v;
  v[0] = (__bf16)a.x; v[1] = (__bf16)a.y; v[2] = (__bf16)a.z; v[3] = (__bf16)a.w;
  v[4] = (__bf16)b.x; v[5] = (__bf16)b.y; v[6] = (__bf16)b.z; v[7] = (__bf16)b.w;
  *(bf16x8*)(o + i) = v;
}

// W[1024][1024] fp32 -> Wt[1024][1024] bf16 transposed; 64x64 tiles.
// T1 points into the QK-concat buffer (rows 1024..2047).
__global__ __launch_bounds__(256) void transpose_w(
    const float* __restrict__ W0, const float* __restrict__ W1,
    const float* __restrict__ W2, __bf16* __restrict__ T0,
    __bf16* __restrict__ T1, __bf16* __restrict__ T2) {
  const float* W = blockIdx.z == 0 ? W0 : (blockIdx.z == 1 ? W1 : W2);
  __bf16* T      = blockIdx.z == 0 ? T0 : (blockIdx.z == 1 ? T1 : T2);
  __shared__ float t[64][65];
  const int e0 = blockIdx.x * 64, d0 = blockIdx.y * 64;
  const int tr = threadIdx.x >> 2, tc = (threadIdx.x & 3) * 16;
  const float* src = W + (long)(d0 + tr) * 1024 + e0 + tc;
#pragma unroll
  for (int i = 0; i < 4; ++i) {
    float4 v = *(const float4*)(src + i * 4);
    t[tr][tc + i * 4 + 0] = v.x;
    t[tr][tc + i * 4 + 1] = v.y;
    t[tr][tc + i * 4 + 2] = v.z;
    t[tr][tc + i * 4 + 3] = v.w;
  }
  __syncthreads();
  __bf16* dst = T + (long)(e0 + tr) * 1024 + d0 + tc;
  bf16x8 v0, v1;
#pragma unroll
  for (int i = 0; i < 8; ++i) v0[i] = (__bf16)t[tc + i][tr];
#pragma unroll
  for (int i = 0; i < 8; ++i) v1[i] = (__bf16)t[tc + 8 + i][tr];
  *(bf16x8*)dst = v0;
  *(bf16x8*)(dst + 8) = v1;
}

// in-place row softmax over 2048 bf16, one block per row, fp32 reduction
__global__ __launch_bounds__(256) void softmax_rows(__bf16* __restrict__ P) {
  __bf16* p = P + (long)blockIdx.x * 2048;
  const int t = threadIdx.x, wid = t >> 6, lane = t & 63;
  bf16x8 v = *(bf16x8*)(p + t * 8);
  float f[8];
  float mx = -1e30f;
#pragma unroll
  for (int i = 0; i < 8; ++i) { f[i] = (float)v[i]; mx = fmaxf(mx, f[i]); }
#pragma unroll
  for (int o = 32; o > 0; o >>= 1) mx = fmaxf(mx, __shfl_xor(mx, o));
  __shared__ float redm[4], reds[4];
  if (lane == 0) redm[wid] = mx;
  __syncthreads();
  mx = fmaxf(fmaxf(redm[0], redm[1]), fmaxf(redm[2], redm[3]));
  float s = 0.f;
#pragma unroll
  for (int i = 0; i < 8; ++i) { f[i] = __expf(f[i] - mx); s += f[i]; }
#pragma unroll
  for (int o = 32; o > 0; o >>= 1) s += __shfl_xor(s, o);
  if (lane == 0) reds[wid] = s;
  __syncthreads();
  s = reds[0] + reds[1] + reds[2] + reds[3];
  const float inv = 1.0f / s;
#pragma unroll
  for (int i = 0; i < 8; ++i) v[i] = (__bf16)(f[i] * inv);
  *(bf16x8*)(p + t * 8) = v;
}

// ---------------------------------------------------------------------------
extern "C" void kernel_launch(void* const* d_in, const int* in_sizes, int n_in,
                              void* d_out, int out_size, void* d_ws,
                              size_t ws_size, hipStream_t stream) {
  const float* x  = (const float*)d_in[0];
  const float* Wq = (const float*)d_in[1];
  const float* bq = (const float*)d_in[2];
  const float* Wk = (const float*)d_in[3];
  const float* bk = (const float*)d_in[4];
  const float* Wv = (const float*)d_in[5];
  const float* bv = (const float*)d_in[6];
  float* out = (float*)d_out;

  char* ws = (char*)d_ws;
  __bf16* xb   = (__bf16*)(ws);                 // 16 MB: x bf16 [8192][1024]
  __bf16* wqkt = (__bf16*)(ws + (16l << 20));   //  4 MB: [Wq^T; Wk^T] [2048][1024]
  __bf16* wvt  = (__bf16*)(ws + (20l << 20));   //  2 MB: Wv^T [1024][1024]
  __bf16* qk   = (__bf16*)(ws + (22l << 20));   // 32 MB: [Q|K] [8192][2048]
  __bf16* vt   = (__bf16*)(ws + (54l << 20));   // 16 MB: V^T [1024][8192]
  __bf16* S    = (__bf16*)(ws + (70l << 20));   // 32 MB: S/P [4][2048][2048]

  convert_x<<<4096, 256, 0, stream>>>(x, xb);
  transpose_w<<<dim3(16, 16, 3), 256, 0, stream>>>(
      Wq, Wk, Wv, wqkt, wqkt + 1024l * 1024, wvt);

  // [Q|K] = xb * [Wq^T;Wk^T]^T + [bq|bk]  (M=8192, N=2048, K=1024)
  gemm3<1, 1, 0><<<dim3(16, 32, 1), 512, 0, stream>>>(
      xb, wqkt, bq, bk, qk, 1024, 1024, 2048, 1024, 0, 0, 0, 1.f);
  // V^T: Vt[e][token] (M=1024 feats, N=8192 tokens), bias per ROW
  gemm3<1, 2, 0><<<dim3(64, 4, 1), 512, 0, stream>>>(
      wvt, xb, bv, nullptr, vt, 1024, 1024, 8192, 1024, 0, 0, 0, 1.f);

  // S = Q K^T * (1/32)  per batch (M=N=2048, K=1024), bf16 out
  gemm3<1, 0, 1><<<dim3(16, 8, 4), 512, 0, stream>>>(
      qk, qk + 1024, nullptr, nullptr, S, 2048, 2048, 2048, 1024,
      2048l * 2048, 2048l * 2048, 2048l * 2048, 0.03125f);

  softmax_rows<<<8192, 256, 0, stream>>>(S);

  // O = P V  per batch (M=2048, N=1024, K=2048), fp32 out to d_out
  gemm3<0, 0, 0><<<dim3(8, 8, 4), 512, 0, stream>>>(
      S, vt, nullptr, nullptr, out, 2048, 8192, 1024, 2048,
      2048l * 2048, 2048, 2048l * 1024, 1.f);
}